// Round 9
// baseline (717.958 us; speedup 1.0000x reference)
//
#include <hip/hip_runtime.h>
#include <math.h>

#define BATCH 4
#define NPTS  8192
#define KNN   16
#define KK    17               // top-17 incl. self (self key: d2 = +0 exactly)
#define NQ    (BATCH*NPTS)     // 32768
#define JMASK 0x1FFFu
#define EMASK 0xFFFFE000u      // top 19 bits of d2 (d2 >= +0 -> uint-sortable)
#define TOTAL_EDGES (BATCH*NPTS*KNN)

#define GC    32
#define GLO   (-4.5f)
#define GINV  (32.0f/9.0f)
#define NCELL (GC*GC*GC)

#define QPB   64               // queries per block (Morton-consecutive)
#define BLOCK 512              // 8 waves; thread (w,l): query l, point-slice w
#define NWAVE 8
#define SLICE (NPTS/NWAVE)     // 1024 points per thread sweep
#define GRIDQ (NQ/QPB)         // 512 blocks (2 per CU, uniform work)
#define WIN   64               // tau0 window (sorted-index neighbors)
#define LCAP  25               // per-(query,slice) LDS list entries (odd stride)
#define LTH   21               // compact when cnt > LTH (max 4 appends between checks)

__device__ __forceinline__ int cell_coord(float x) {
    int c = (int)floorf((x - GLO) * GINV);
    return min(GC - 1, max(0, c));
}
__device__ __forceinline__ unsigned spread5(unsigned v) {
    v &= 31u;
    v = (v | (v << 8)) & 0x100Fu;
    v = (v | (v << 4)) & 0x10C3u;
    v = (v | (v << 2)) & 0x1249u;
    return v;
}
__device__ __forceinline__ unsigned morton_id(float x, float y, float z) {
    return spread5((unsigned)cell_coord(x)) | (spread5((unsigned)cell_coord(y)) << 1)
         | (spread5((unsigned)cell_coord(z)) << 2);
}
// p = (-2xj,-2yj,-2zj,sqj); key = truncated d2 | index (self -> d2 = +0 exact)
__device__ __forceinline__ unsigned mkkey(const float4 p, float xi, float yi,
                                          float zi, float sqi, unsigned j) {
    const float e  = fmaf(p.x, xi, fmaf(p.y, yi, p.z * zi)) + p.w;
    const float d2 = e + sqi;
    return (__float_as_uint(d2) & EMASK) | j;
}
__device__ __forceinline__ void ins17(unsigned (&a)[KK], unsigned key) {
    #pragma unroll
    for (int k = KK - 1; k >= 1; --k) a[k] = min(a[k], max(a[k - 1], key));
    a[0] = min(a[0], key);
}

// ---- build kernels (verified, absmax 0.0) ----
__global__ void pel_hist(const float* __restrict__ pref, unsigned* __restrict__ hist,
                         float* __restrict__ acc, unsigned* __restrict__ bcnt) {
    const int idx = blockIdx.x * 256 + threadIdx.x;
    if (idx == 0) { acc[0] = 0.0f; bcnt[0] = 0u; }
    const int b = idx >> 13;
    const unsigned mid = morton_id(pref[3*idx], pref[3*idx+1], pref[3*idx+2]);
    atomicAdd(&hist[b * NCELL + mid], 1u);
}
__global__ __launch_bounds__(1024)
void pel_scan(const unsigned* __restrict__ hist, unsigned* __restrict__ off) {
    __shared__ unsigned s[1024];
    const unsigned* h = hist + blockIdx.x * NCELL;
    unsigned*       o = off  + blockIdx.x * NCELL;
    const int t = threadIdx.x;
    unsigned v[32], tot = 0;
    #pragma unroll
    for (int k = 0; k < 32; ++k) { v[k] = h[t * 32 + k]; tot += v[k]; }
    s[t] = tot;
    __syncthreads();
    for (int d = 1; d < 1024; d <<= 1) {
        const unsigned add = (t >= d) ? s[t - d] : 0u;
        __syncthreads();
        s[t] += add;
        __syncthreads();
    }
    unsigned run = s[t] - tot;
    #pragma unroll
    for (int k = 0; k < 32; ++k) { o[t * 32 + k] = run; run += v[k]; }
}
__global__ void pel_scatter(const float* __restrict__ pref, const float* __restrict__ pts,
                            unsigned* __restrict__ off,
                            float4* __restrict__ p4r, float4* __restrict__ p4p) {
    const int idx = blockIdx.x * 256 + threadIdx.x;
    const int b = idx >> 13;
    const float x = pref[3*idx], y = pref[3*idx+1], z = pref[3*idx+2];
    const unsigned mid = morton_id(x, y, z);
    const unsigned pos = atomicAdd(&off[b * NCELL + mid], 1u);
    p4r[b * NPTS + pos] = make_float4(-2.f*x, -2.f*y, -2.f*z, fmaf(x, x, fmaf(y, y, z*z)));
    const float px = pts[3*idx], py = pts[3*idx+1], pz = pts[3*idx+2];
    p4p[b * NPTS + pos] = make_float4(-2.f*px, -2.f*py, -2.f*pz,
                                      fmaf(px, px, fmaf(py, py, pz*pz)));
}

// ---- query kernel: uniform brute force, rare-path LDS-deferred selection ----
// Round-9 synthesis of R7+R8 post-mortems:
//  * R7 sweep (vector broadcast loads, VGPR prefetch) was right; its tax was
//    the 34-op register ins17 firing at wave level on ~40% of steps (~70us).
//  * R8's fix direction (defer to LDS, merge 64-wide) was right; its bugs
//    were the UNCONDITIONAL ds_write per step (4.2M wave ds_writes, 4.9M
//    conflict cyc) and readfirstlane forcing scalar loads that thrash the
//    shared K$ (stall 88->417us).
// Now: per 4-pt bundle, 4 keys + 4 cmps + ONE __any -> wave skips (cbranch)
// when no lane accepts (~37% of bundles); else 4 exec-masked 2-op appends.
// ds_writes only for accepted keys (~4/lane total). Compaction at cnt>LTH
// rebuilds top-17 in regs, tightens tauL (dropped keys beaten by 17 same-
// slice keys -> provably safe). Post-barrier merge: all 64 lanes ins17 at
// the same trip (cost amortized 64-wide). Work uniform; no filter, no tail.
__global__ __launch_bounds__(BLOCK, 2)
void pel_query(const float4* __restrict__ P4r, const float4* __restrict__ P4p,
               float* __restrict__ acc_ws, unsigned* __restrict__ bcnt,
               float* __restrict__ out)
{
    __shared__ unsigned s_list[BLOCK * LCAP];     // 50 KB candidate lists
    __shared__ int s_cnt[BLOCK];                  // 2 KB
    __shared__ float s_part[NWAVE];

    const int t = threadIdx.x;
    const int l = t & 63, w = t >> 6;
    const int q = blockIdx.x * QPB + l;
    const int b = q >> 13;
    const int i = q & (NPTS - 1);

    const float4* __restrict__ Pq = P4r + b * NPTS;
    const float4* __restrict__ Pp = P4p + b * NPTS;

    const float4 self = Pq[i];
    const float xi = -0.5f * self.x, yi = -0.5f * self.y, zi = -0.5f * self.z;
    const float sqi = self.w;

    // ---- Phase W: tau0 = exact 17th of the 64-pt Morton window (regs) ----
    unsigned t17[KK];
    #pragma unroll
    for (int k = 0; k < KK; ++k) t17[k] = 0xFFFFFFFFu;
    const int w0 = min(max(i - WIN / 2, 0), NPTS - WIN);
    for (int u = 0; u < WIN; ++u) {
        const unsigned key = mkkey(Pq[w0 + u], xi, yi, zi, sqi, (unsigned)(w0 + u));
        if (key <= t17[KK - 1]) ins17(t17, key);
    }
    unsigned tauL = t17[KK - 1];   // >= true 17th (window is a subset)

    // ---- Phase B: sweep my 1024-pt slice; accepts -> LDS list (rare path) ----
    // Superset proof: any true top-17 key k of query q satisfies
    // k <= global17 <= 17th-of-any-subset, so k passes every tauL it meets;
    // slices partition the batch, so k lands in exactly one list.
    unsigned* myl = &s_list[t * LCAP];
    int cnt = 0;
    const int jb = w << 10;       // wave-uniform; 64 lanes broadcast-load
    float4 a0 = Pq[jb + 0], a1 = Pq[jb + 1], a2 = Pq[jb + 2], a3 = Pq[jb + 3];
    float4 b0 = Pq[jb + 4], b1 = Pq[jb + 5], b2 = Pq[jb + 6], b3 = Pq[jb + 7];
    for (int j = 0; j < SLICE; j += 4) {
        const int jn = jb + ((j + 8) & (SLICE - 1));      // depth-2 prefetch
        const float4 n0 = Pq[jn],     n1 = Pq[jn + 1];
        const float4 n2 = Pq[jn + 2], n3 = Pq[jn + 3];
        const unsigned k0 = mkkey(a0, xi, yi, zi, sqi, (unsigned)(jb + j));
        const unsigned k1 = mkkey(a1, xi, yi, zi, sqi, (unsigned)(jb + j + 1));
        const unsigned k2 = mkkey(a2, xi, yi, zi, sqi, (unsigned)(jb + j + 2));
        const unsigned k3 = mkkey(a3, xi, yi, zi, sqi, (unsigned)(jb + j + 3));
        const bool c0 = k0 <= tauL, c1 = k1 <= tauL;
        const bool c2 = k2 <= tauL, c3 = k3 <= tauL;
        if (__any(c0 | c1 | c2 | c3)) {           // wave skips dead bundles
            if (c0) myl[cnt++] = k0;
            if (c1) myl[cnt++] = k1;
            if (c2) myl[cnt++] = k2;
            if (c3) myl[cnt++] = k3;
            if (cnt > LTH) {                      // rare: rebuild 17, tighten
                unsigned a[KK];
                #pragma unroll
                for (int k = 0; k < KK; ++k) a[k] = 0xFFFFFFFFu;
                #pragma unroll 1
                for (int n = 0; n < cnt; ++n) {
                    const unsigned vk = myl[n];
                    if (vk <= a[KK - 1]) ins17(a, vk);
                }
                #pragma unroll
                for (int k = 0; k < KK; ++k) myl[k] = a[k];
                cnt = KK; tauL = a[KK - 1];
            }
        }
        a0 = b0; a1 = b1; a2 = b2; a3 = b3;
        b0 = n0; b1 = n1; b2 = n2; b3 = n3;
    }
    s_cnt[t] = cnt;
    __syncthreads();

    // ---- Phase C: merge the query's 8 slice lists -> exact sorted top-17 ----
    // All 64 lanes insert at the same trip -> ins17 amortizes 64-wide.
    unsigned c17[KK];
    #pragma unroll
    for (int k = 0; k < KK; ++k) c17[k] = 0xFFFFFFFFu;
    #pragma unroll 1
    for (int d = 0; d < NWAVE; ++d) {
        const int ts = (((w + d) & (NWAVE - 1)) << 6) | l;
        const unsigned* sl = &s_list[ts * LCAP];
        const int cn = s_cnt[ts];
        #pragma unroll 1
        for (int n = 0; n < cn; ++n) {
            const unsigned vk = sl[n];
            if (vk <= c17[KK - 1]) ins17(c17, vk);   // unsorted lists: guard
        }
    }
    // c17 = exact sorted top-17 incl self, identical across the 8 owners

    // ---- Phase D: |dr - dp| over ranks w, w+8, w+16 of the shared list ----
    const float4 selfp = Pp[i];
    const float pxi = -0.5f * selfp.x, pyi = -0.5f * selfp.y, pzi = -0.5f * selfp.z;
    float accv = 0.0f;
    for (int r = w; r < KK; r += NWAVE) {
        const int j = (int)(c17[r] & JMASK);
        const float4 pr = Pq[j];
        const float er  = fmaf(pr.x, xi, fmaf(pr.y, yi, pr.z * zi)) + pr.w;
        const float d2r = fmaxf(er + sqi, 0.0f);
        const float4 pp = Pp[j];
        const float ep  = fmaf(pp.x, pxi, fmaf(pp.y, pyi, pp.z * pzi)) + pp.w;
        const float d2p = fmaxf(ep + selfp.w, 0.0f);
        accv += fabsf(sqrtf(d2r) - sqrtf(d2p));   // self term contributes 0
    }

    #pragma unroll
    for (int o = 32; o > 0; o >>= 1) accv += __shfl_down(accv, o, 64);
    if (l == 0) s_part[w] = accv;
    __syncthreads();
    if (t == 0) {
        float s = 0.0f;
        #pragma unroll
        for (int w2 = 0; w2 < NWAVE; ++w2) s += s_part[w2];
        atomicAdd(acc_ws, s);
        __threadfence();
        const unsigned old = atomicAdd(bcnt, 1u);
        if (old == GRIDQ - 1) {
            __threadfence();
            const float total = atomicAdd(acc_ws, 0.0f);
            out[0] = total * (1.0f / (float)TOTAL_EDGES);
        }
    }
}

extern "C" void kernel_launch(void* const* d_in, const int* in_sizes, int n_in,
                              void* d_out, int out_size, void* d_ws, size_t ws_size,
                              hipStream_t stream) {
    const float* pref = (const float*)d_in[0];
    const float* pts  = (const float*)d_in[1];
    // ws: [P4r 512K (alias hist)][P4p 512K][off 512K][acc,bcnt]
    float4*   P4r  = (float4*)d_ws;
    float4*   P4p  = P4r + NQ;
    unsigned* hist = (unsigned*)d_ws;                      // dead after scan
    unsigned* off  = (unsigned*)((char*)d_ws + 1048576);   // dead after scatter
    float*    acc  = (float*)((char*)d_ws + 1581056);
    unsigned* bcnt = (unsigned*)(acc + 1);
    float*    out  = (float*)d_out;

    hipMemsetAsync(hist, 0, BATCH * NCELL * sizeof(unsigned), stream);
    pel_hist   <<<NQ / 256, 256, 0, stream>>>(pref, hist, acc, bcnt);
    pel_scan   <<<BATCH, 1024, 0, stream>>>(hist, off);
    pel_scatter<<<NQ / 256, 256, 0, stream>>>(pref, pts, off, P4r, P4p);
    pel_query  <<<GRIDQ, BLOCK, 0, stream>>>(P4r, P4p, acc, bcnt, out);
}

// Round 10
// 330.426 us; speedup vs baseline: 2.1728x; 2.1728x over previous
//
#include <hip/hip_runtime.h>
#include <math.h>

#define BATCH 4
#define NPTS  8192
#define KNN   16
#define KK    17               // top-17 incl. self (self key: d2 = +0 exactly)
#define NQ    (BATCH*NPTS)     // 32768
#define JMASK 0x1FFFu
#define EMASK 0xFFFFE000u      // top 19 bits of d2 (d2 >= +0 -> uint-sortable)
#define TOTAL_EDGES (BATCH*NPTS*KNN)

#define GC    32
#define GLO   (-4.5f)
#define GINV  (32.0f/9.0f)
#define NCELL (GC*GC*GC)

#define QPB   32               // queries per block (Morton-consecutive)
#define BLOCK 512              // 16 slices: thread (w,l): query l, slice w
#define NSLC  16
#define SLICE (NPTS/NSLC)      // 512 points per thread sweep
#define GRIDQ (NQ/QPB)         // 1024 blocks (4 per CU: 32 waves/CU residency)
#define WIN   128              // tau0 window (computed once per query now)

__device__ __forceinline__ int cell_coord(float x) {
    int c = (int)floorf((x - GLO) * GINV);
    return min(GC - 1, max(0, c));
}
__device__ __forceinline__ unsigned spread5(unsigned v) {
    v &= 31u;
    v = (v | (v << 8)) & 0x100Fu;
    v = (v | (v << 4)) & 0x10C3u;
    v = (v | (v << 2)) & 0x1249u;
    return v;
}
__device__ __forceinline__ unsigned morton_id(float x, float y, float z) {
    return spread5((unsigned)cell_coord(x)) | (spread5((unsigned)cell_coord(y)) << 1)
         | (spread5((unsigned)cell_coord(z)) << 2);
}
// p = (-2xj,-2yj,-2zj,sqj); key = truncated d2 | index (self -> d2 = +0 exact)
__device__ __forceinline__ unsigned mkkey(const float4 p, float xi, float yi,
                                          float zi, float sqi, unsigned j) {
    const float e  = fmaf(p.x, xi, fmaf(p.y, yi, p.z * zi)) + p.w;
    const float d2 = e + sqi;
    return (__float_as_uint(d2) & EMASK) | j;
}
__device__ __forceinline__ void ins17(unsigned (&a)[KK], unsigned key) {
    #pragma unroll
    for (int k = KK - 1; k >= 1; --k) a[k] = min(a[k], max(a[k - 1], key));
    a[0] = min(a[0], key);
}

// ---- build kernels (verified, absmax 0.0) ----
__global__ void pel_hist(const float* __restrict__ pref, unsigned* __restrict__ hist,
                         float* __restrict__ acc, unsigned* __restrict__ bcnt) {
    const int idx = blockIdx.x * 256 + threadIdx.x;
    if (idx == 0) { acc[0] = 0.0f; bcnt[0] = 0u; }
    const int b = idx >> 13;
    const unsigned mid = morton_id(pref[3*idx], pref[3*idx+1], pref[3*idx+2]);
    atomicAdd(&hist[b * NCELL + mid], 1u);
}
__global__ __launch_bounds__(1024)
void pel_scan(const unsigned* __restrict__ hist, unsigned* __restrict__ off) {
    __shared__ unsigned s[1024];
    const unsigned* h = hist + blockIdx.x * NCELL;
    unsigned*       o = off  + blockIdx.x * NCELL;
    const int t = threadIdx.x;
    unsigned v[32], tot = 0;
    #pragma unroll
    for (int k = 0; k < 32; ++k) { v[k] = h[t * 32 + k]; tot += v[k]; }
    s[t] = tot;
    __syncthreads();
    for (int d = 1; d < 1024; d <<= 1) {
        const unsigned add = (t >= d) ? s[t - d] : 0u;
        __syncthreads();
        s[t] += add;
        __syncthreads();
    }
    unsigned run = s[t] - tot;
    #pragma unroll
    for (int k = 0; k < 32; ++k) { o[t * 32 + k] = run; run += v[k]; }
}
__global__ void pel_scatter(const float* __restrict__ pref, const float* __restrict__ pts,
                            unsigned* __restrict__ off,
                            float4* __restrict__ p4r, float4* __restrict__ p4p) {
    const int idx = blockIdx.x * 256 + threadIdx.x;
    const int b = idx >> 13;
    const float x = pref[3*idx], y = pref[3*idx+1], z = pref[3*idx+2];
    const unsigned mid = morton_id(x, y, z);
    const unsigned pos = atomicAdd(&off[b * NCELL + mid], 1u);
    p4r[b * NPTS + pos] = make_float4(-2.f*x, -2.f*y, -2.f*z, fmaf(x, x, fmaf(y, y, z*z)));
    const float px = pts[3*idx], py = pts[3*idx+1], pz = pts[3*idx+2];
    p4p[b * NPTS + pos] = make_float4(-2.f*px, -2.f*py, -2.f*pz,
                                      fmaf(px, px, fmaf(py, py, pz*pz)));
}

// ---- query kernel: R7 brute-force sweep + occupancy & window fixes ----
// Round-10. R8/R9 proved LDS-deferred selection is a dead end (ds_write
// floods / broken load pipeline); R7's guarded register-ins17 sweep stands.
// R7's 44% stall was structural: 512 blocks = 2/CU = 16 waves/CU lockstep,
// 8x-redundant 64-pt gather windows, serial break-merge. Fixes:
//  * QPB=32, 16 slices x 512 pts -> 1024 blocks, 4/CU (35 KB LDS),
//    up to 32 waves/CU to hide L1/L2 latency; per-thread sweep halved.
//  * window computed ONCE per query (t<32) at WIN=128 (tighter tau0 ->
//    fewer divergent sweep inserts), shared via s_tau0 + one barrier.
//  * depth-2 prefetch rotation; launch_bounds(512,4) for register headroom.
// Selection math, pools, break-merge, rank-split Phase D: R7 verbatim.
__global__ __launch_bounds__(BLOCK, 4)
void pel_query(const float4* __restrict__ P4r, const float4* __restrict__ P4p,
               float* __restrict__ acc_ws, unsigned* __restrict__ bcnt,
               float* __restrict__ out)
{
    __shared__ unsigned s_pool[KK][BLOCK];        // 34 KB (columns: conflict-free)
    __shared__ unsigned s_tau0[QPB];
    __shared__ float s_part[BLOCK / 64];

    const int t = threadIdx.x;
    const int l = t & (QPB - 1), w = t >> 5;      // query l, slice w
    const int q = blockIdx.x * QPB + l;
    const int b = q >> 13;
    const int i = q & (NPTS - 1);

    const float4* __restrict__ Pq = P4r + b * NPTS;
    const float4* __restrict__ Pp = P4p + b * NPTS;

    const float4 self = Pq[i];
    const float xi = -0.5f * self.x, yi = -0.5f * self.y, zi = -0.5f * self.z;
    const float sqi = self.w;

    // ---- Phase W (t<32 only): tau0 = exact 17th of 128-pt Morton window ----
    if (t < QPB) {
        unsigned t17[KK];
        #pragma unroll
        for (int k = 0; k < KK; ++k) t17[k] = 0xFFFFFFFFu;
        const int w0 = min(max(i - WIN / 2, 0), NPTS - WIN);
        for (int u = 0; u < WIN; ++u) {
            const unsigned key = mkkey(Pq[w0 + u], xi, yi, zi, sqi, (unsigned)(w0 + u));
            if (key <= t17[KK - 1]) ins17(t17, key);
        }
        s_tau0[t] = t17[KK - 1];   // >= true 17th (window is a subset)
    }
    __syncthreads();

    // ---- Phase B: sweep my 512-pt slice, register sorted-17 pool ----
    // Streaming top-k: key rejected by tauL = min(tau0, own 17th) is beaten
    // by 17 same-slice keys -> not in the query's top-17. Union of the 16
    // slice pools contains the true top-17. Depth-2 4-pt prefetch rotation.
    unsigned tauL = s_tau0[l];
    unsigned c17[KK];
    #pragma unroll
    for (int k = 0; k < KK; ++k) c17[k] = 0xFFFFFFFFu;
    const int jb = w << 9;
    float4 a0 = Pq[jb + 0], a1 = Pq[jb + 1], a2 = Pq[jb + 2], a3 = Pq[jb + 3];
    float4 b0 = Pq[jb + 4], b1 = Pq[jb + 5], b2 = Pq[jb + 6], b3 = Pq[jb + 7];
    for (int j = 0; j < SLICE; j += 4) {
        const int jn = jb + ((j + 8) & (SLICE - 1));      // depth-2 prefetch
        const float4 n0 = Pq[jn],     n1 = Pq[jn + 1];
        const float4 n2 = Pq[jn + 2], n3 = Pq[jn + 3];
        unsigned key;
        key = mkkey(a0, xi, yi, zi, sqi, (unsigned)(jb + j));
        if (key <= tauL) { ins17(c17, key); tauL = min(tauL, c17[KK - 1]); }
        key = mkkey(a1, xi, yi, zi, sqi, (unsigned)(jb + j + 1));
        if (key <= tauL) { ins17(c17, key); tauL = min(tauL, c17[KK - 1]); }
        key = mkkey(a2, xi, yi, zi, sqi, (unsigned)(jb + j + 2));
        if (key <= tauL) { ins17(c17, key); tauL = min(tauL, c17[KK - 1]); }
        key = mkkey(a3, xi, yi, zi, sqi, (unsigned)(jb + j + 3));
        if (key <= tauL) { ins17(c17, key); tauL = min(tauL, c17[KK - 1]); }
        a0 = b0; a1 = b1; a2 = b2; a3 = b3;
        b0 = n0; b1 = n1; b2 = n2; b3 = n3;
    }

    // ---- Phase C: publish partials, merge 16 sorted pools -> exact 17 ----
    #pragma unroll
    for (int k = 0; k < KK; ++k) s_pool[k][t] = c17[k];
    __syncthreads();
    #pragma unroll 1
    for (int d = 1; d < NSLC; ++d) {
        const int t2 = ((((w + d) & (NSLC - 1)) << 5) | l);
        #pragma unroll 1
        for (int k = 0; k < KK; ++k) {
            const unsigned vk = s_pool[k][t2];
            if (vk >= c17[KK - 1]) break;   // sorted source: nothing more fits
            ins17(c17, vk);
        }
    }
    // c17 = exact sorted top-17 incl self, identical across the 16 owners
    // (slices disjoint -> keys unique -> unique set; pure integer min/max)

    // ---- Phase D: |dr - dp| over ranks w, w+16 of the shared list ----
    const float4 selfp = Pp[i];
    const float pxi = -0.5f * selfp.x, pyi = -0.5f * selfp.y, pzi = -0.5f * selfp.z;
    float accv = 0.0f;
    for (int r = w; r < KK; r += NSLC) {
        const int j = (int)(c17[r] & JMASK);
        const float4 pr = Pq[j];
        const float er  = fmaf(pr.x, xi, fmaf(pr.y, yi, pr.z * zi)) + pr.w;
        const float d2r = fmaxf(er + sqi, 0.0f);
        const float4 pp = Pp[j];
        const float ep  = fmaf(pp.x, pxi, fmaf(pp.y, pyi, pp.z * pzi)) + pp.w;
        const float d2p = fmaxf(ep + selfp.w, 0.0f);
        accv += fabsf(sqrtf(d2r) - sqrtf(d2p));   // self term contributes 0
    }

    #pragma unroll
    for (int o = 32; o > 0; o >>= 1) accv += __shfl_down(accv, o, 64);
    if ((t & 63) == 0) s_part[t >> 6] = accv;
    __syncthreads();
    if (t == 0) {
        float s = 0.0f;
        #pragma unroll
        for (int w2 = 0; w2 < BLOCK / 64; ++w2) s += s_part[w2];
        atomicAdd(acc_ws, s);
        __threadfence();
        const unsigned old = atomicAdd(bcnt, 1u);
        if (old == GRIDQ - 1) {
            __threadfence();
            const float total = atomicAdd(acc_ws, 0.0f);
            out[0] = total * (1.0f / (float)TOTAL_EDGES);
        }
    }
}

extern "C" void kernel_launch(void* const* d_in, const int* in_sizes, int n_in,
                              void* d_out, int out_size, void* d_ws, size_t ws_size,
                              hipStream_t stream) {
    const float* pref = (const float*)d_in[0];
    const float* pts  = (const float*)d_in[1];
    // ws: [P4r 512K (alias hist)][P4p 512K][off 512K][acc,bcnt]
    float4*   P4r  = (float4*)d_ws;
    float4*   P4p  = P4r + NQ;
    unsigned* hist = (unsigned*)d_ws;                      // dead after scan
    unsigned* off  = (unsigned*)((char*)d_ws + 1048576);   // dead after scatter
    float*    acc  = (float*)((char*)d_ws + 1581056);
    unsigned* bcnt = (unsigned*)(acc + 1);
    float*    out  = (float*)d_out;

    hipMemsetAsync(hist, 0, BATCH * NCELL * sizeof(unsigned), stream);
    pel_hist   <<<NQ / 256, 256, 0, stream>>>(pref, hist, acc, bcnt);
    pel_scan   <<<BATCH, 1024, 0, stream>>>(hist, off);
    pel_scatter<<<NQ / 256, 256, 0, stream>>>(pref, pts, off, P4r, P4p);
    pel_query  <<<GRIDQ, BLOCK, 0, stream>>>(P4r, P4p, acc, bcnt, out);
}